// Round 2
// baseline (1207.693 us; speedup 1.0000x reference)
//
#include <hip/hip_runtime.h>

// RecyclingEmbedder: out[i][j][p] = b[p] + (bin(d_ij) >= 0 ? W[p][bin] : 0)
// where d_ij = |x_i - x_j|^2 and bin edges are linspace(3.25,20.75,15)^2 with
// strict (>lower, <upper) comparisons. Output is a 16-row table lookup ->
// pure write-BW problem (1.208 GB fp32 out).

#define NBINS 15
#define NPTS  1536
#define DPAIR 128

typedef float f32x4 __attribute__((ext_vector_type(4)));

__global__ __launch_bounds__(256) void recycling_embedder_kernel(
    const float* __restrict__ x,   // [NPTS,3]
    const float* __restrict__ W,   // [DPAIR,NBINS] row-major
    const float* __restrict__ b,   // [DPAIR]
    float* __restrict__ out,       // [NPTS,NPTS,DPAIR]
    unsigned total_f4) {
    // LDS: row table (16 rows x 128 floats = 8 KB) + x (18 KB) = 26 KB
    __shared__ float table[16 * DPAIR];
    __shared__ float xs[NPTS * 3];

    // squared bin edges: edges are exact multiples of 0.25 -> exact fp32;
    // square rounds identically to numpy's **2 in float32.
    float bins[NBINS];
#pragma unroll
    for (int k = 0; k < NBINS; ++k) {
        float e = 3.25f + 1.25f * (float)k;
        bins[k] = e * e;
    }

    // Build row table: idx 0 -> b only (no bin fired); idx k>=1 -> b + W[:,k-1]
    for (int e = threadIdx.x; e < 16 * DPAIR; e += blockDim.x) {
        int idx = e >> 7;        // 0..15
        int p   = e & (DPAIR - 1);
        float v = b[p];
        if (idx > 0) v += W[p * NBINS + (idx - 1)];
        table[e] = v;
    }
    for (int e = threadIdx.x; e < NPTS * 3; e += blockDim.x) xs[e] = x[e];
    __syncthreads();

    const f32x4* table4 = (const f32x4*)table;
    f32x4* out4 = (f32x4*)out;

    unsigned stride = gridDim.x * blockDim.x;
    for (unsigned g = blockIdx.x * blockDim.x + threadIdx.x; g < total_f4; g += stride) {
        unsigned pair   = g >> 5;       // which (i,j) pair
        unsigned within = g & 31u;      // which float4 of the 128-float row
        unsigned i = pair / NPTS;       // compiler magic-mul for const divide
        unsigned j = pair - i * NPTS;

        float d;
        {
            // Match numpy bit-exactly: individually-rounded squares, then
            // left-to-right sum; no fma contraction.
#pragma clang fp contract(off)
            float dx = xs[i * 3 + 0] - xs[j * 3 + 0];
            float dy = xs[i * 3 + 1] - xs[j * 3 + 1];
            float dz = xs[i * 3 + 2] - xs[j * 3 + 2];
            d = dx * dx + dy * dy + dz * dz;
        }

        // cnt = #edges strictly below d. If d equals ANY edge exactly, the
        // strict (>,<) pair makes the one-hot all-zero -> row = b (idx 0).
        int cnt = 0;
        int eq = 0;
#pragma unroll
        for (int k = 0; k < NBINS; ++k) {
            cnt += (d > bins[k]) ? 1 : 0;
            eq  |= (d == bins[k]) ? 1 : 0;
        }
        int idx = eq ? 0 : cnt;

        f32x4 v = table4[idx * (DPAIR / 4) + within];
        __builtin_nontemporal_store(v, out4 + g);
    }
}

extern "C" void kernel_launch(void* const* d_in, const int* in_sizes, int n_in,
                              void* d_out, int out_size, void* d_ws, size_t ws_size,
                              hipStream_t stream) {
    const float* x = (const float*)d_in[0];
    const float* W = (const float*)d_in[1];
    const float* b = (const float*)d_in[2];
    float* out = (float*)d_out;

    const unsigned total_f4 = (unsigned)NPTS * NPTS * (DPAIR / 4); // 75,497,472
    // 26 KB LDS -> 6 blocks/CU; 1536 blocks = full residency on 256 CUs,
    // grid-stride covers the rest (192 iters/thread).
    dim3 grid(1536), block(256);
    recycling_embedder_kernel<<<grid, block, 0, stream>>>(x, W, b, out, total_f4);
}

// Round 3
// 1177.707 us; speedup vs baseline: 1.0255x; 1.0255x over previous
//
#include <hip/hip_runtime.h>

// RecyclingEmbedder: out[i][j][p] = b[p] + (bin(d_ij) fired ? W[p][bin] : 0)
// d_ij = |x_i - x_j|^2, bins = linspace(3.25,20.75,15)^2, strict >lower & <upper.
// Output = 16-row table lookup -> pure write-BW problem (1.208 GB fp32).
//
// R2 lesson: nontemporal stores ran at ~1.0 TB/s (6x off); harness fill kernel
// hits 6.2 TB/s with PLAIN stores. This version: plain stores + per-row idx
// precompute so the streaming loop is 2 LDS reads + 1 store per float4.

#define NBINS 15
#define NPTS  1536
#define DPAIR 128
#define ROW_F4 (NPTS * DPAIR / 4)   // 49152 float4 per output row i

typedef float f32x4 __attribute__((ext_vector_type(4)));

__global__ __launch_bounds__(256) void recycling_embedder_kernel(
    const float* __restrict__ x,   // [NPTS,3]
    const float* __restrict__ W,   // [DPAIR,NBINS] row-major
    const float* __restrict__ b,   // [DPAIR]
    float* __restrict__ out) {     // [NPTS,NPTS,DPAIR]
    __shared__ float table[16 * DPAIR];       // 8 KB: row 0 = b, row k = b + W[:,k-1]
    __shared__ unsigned char idx_lds[NPTS];   // 1.5 KB: bin index per j for this block's i

    const int i = blockIdx.x;
    const int t = threadIdx.x;

    // squared bin edges: all edges are exact multiples of 0.25 -> exact fp32;
    // squaring rounds identically to numpy's **2 in float32.
    float bins[NBINS];
#pragma unroll
    for (int k = 0; k < NBINS; ++k) {
        float e = 3.25f + 1.25f * (float)k;
        bins[k] = e * e;
    }

    // Build row table.
    for (int e = t; e < 16 * DPAIR; e += 256) {
        int row = e >> 7;            // 0..15
        int p   = e & (DPAIR - 1);
        float v = b[p];
        if (row > 0) v += W[p * NBINS + (row - 1)];
        table[e] = v;
    }

    // Precompute bin index for every j (this block's fixed i).
    const float xi0 = x[i * 3 + 0];
    const float xi1 = x[i * 3 + 1];
    const float xi2 = x[i * 3 + 2];
    for (int j = t; j < NPTS; j += 256) {
        float d;
        {
            // Bit-exact vs numpy: individually-rounded squares, left-to-right
            // sum, no fma contraction.
#pragma clang fp contract(off)
            float dx = xi0 - x[j * 3 + 0];
            float dy = xi1 - x[j * 3 + 1];
            float dz = xi2 - x[j * 3 + 2];
            d = dx * dx + dy * dy + dz * dz;
        }
        int cnt = 0, eq = 0;
#pragma unroll
        for (int k = 0; k < NBINS; ++k) {
            cnt += (d > bins[k]) ? 1 : 0;
            eq  |= (d == bins[k]) ? 1 : 0;
        }
        // exact edge hit -> one-hot all zero -> row 0 (b only)
        idx_lds[j] = (unsigned char)(eq ? 0 : cnt);
    }
    __syncthreads();

    // Streaming phase: 192 iterations/thread, fully coalesced 1 KiB/wave-store.
    const f32x4* table4 = (const f32x4*)table;
    f32x4* orow = (f32x4*)out + (size_t)i * ROW_F4;
#pragma unroll 4
    for (int l = t; l < ROW_F4; l += 256) {
        int j      = l >> 5;       // pair column
        int within = l & 31;       // float4 within the 128-float feature row
        int idx    = idx_lds[j];   // broadcast within half-wave
        orow[l] = table4[idx * (DPAIR / 4) + within];
    }
}

extern "C" void kernel_launch(void* const* d_in, const int* in_sizes, int n_in,
                              void* d_out, int out_size, void* d_ws, size_t ws_size,
                              hipStream_t stream) {
    const float* x = (const float*)d_in[0];
    const float* W = (const float*)d_in[1];
    const float* b = (const float*)d_in[2];
    float* out = (float*)d_out;

    // One block per output row i: 1536 blocks = 6 blocks/CU, 24 waves/CU.
    dim3 grid(NPTS), block(256);
    recycling_embedder_kernel<<<grid, block, 0, stream>>>(x, W, b, out);
}